// Round 7
// baseline (251.795 us; speedup 1.0000x reference)
//
#include <hip/hip_runtime.h>
#include <math.h>

#pragma clang fp contract(off)

#define A_TOTAL 196416
#define BATCH 8
#define KTOT 4576
#define NLEV 5
#define MSPLIT 16
#define RCAP 6144        // per-(b,l) candidate cap (typical cnt ~1.2k)
#define NPARTS 12        // rank parts: 12*512 == RCAP (256-thr blocks, 2 elems/thr)

static __device__ const int d_aoff[NLEV] = {0, 147456, 184320, 193536, 195840};
static __device__ const int d_n[NLEV]    = {147456, 36864, 9216, 2304, 576};
static __device__ const int d_k[NLEV]    = {1000, 1000, 1000, 1000, 576};
// histogram slice-splits per level (13 parts per batch)
static __device__ const int d_spl[NLEV]  = {8, 2, 1, 1, 1};
static __device__ const int d_bp[NLEV]   = {0, 8, 10, 11, 12};
static __device__ const int d_pb_l[13]    = {0,0,0,0,0,0,0,0,1,1,2,3,4};
static __device__ const int d_pb_part[13] = {0,1,2,3,4,5,6,7,0,1,0,0,0};

// Exact-equivalence constant for "RN(inter/denom) > 0.7f":
//   RN(q) > 0.7f  <=>  q >= midpoint(0.7f, nextafter(0.7f))  <=>
//   (double)inter >= TM_IOU * (double)denom  exactly (<=49 sig bits).
#define TM_IOU (0.699999988079071044921875 + 0x1p-25)

// monotone map: f32 -> u32 preserving order (no NaNs in this data); invertible
__device__ inline unsigned int mono(float f) {
  unsigned int u = __float_as_uint(f);
  return (u & 0x80000000u) ? ~u : (u | 0x80000000u);
}
__device__ inline float imono(unsigned int m) {
  return __uint_as_float((m & 0x80000000u) ? (m & 0x7FFFFFFFu) : ~m);
}

// binary searches on a descending-sorted array
__device__ inline int cnt_gt(const float* A, int n, float s) {  // #{A[i] > s}
  int lo = 0, hi = n;
  while (lo < hi) { int mid = (lo + hi) >> 1; if (A[mid] > s) lo = mid + 1; else hi = mid; }
  return lo;
}
__device__ inline int cnt_ge(const float* A, int n, float s) {  // #{A[i] >= s}
  int lo = 0, hi = n;
  while (lo < hi) { int mid = (lo + hi) >> 1; if (A[mid] >= s) lo = mid + 1; else hi = mid; }
  return lo;
}

// ---------------------------------------------------------------------------
// K1: per-(b,l,part) private 4096-bin histogram of mono(obj) top-12 bits.
// Block 0 zero-inits cnt_hi/cnt_mid/maxblk; the pb==0 block of each batch
// also zero-fills that batch's output slice.
// ---------------------------------------------------------------------------
__global__ __launch_bounds__(1024) void k_hist(const float* __restrict__ obj,
                                               int* __restrict__ hist_g,
                                               int* __restrict__ cnt_hi,
                                               int* __restrict__ cnt_mid,
                                               float* __restrict__ maxblk,
                                               float* __restrict__ out) {
  int blk = blockIdx.x;
  int tid = threadIdx.x;
  if (blk == 0) {
    for (int i = tid; i < 40 * NPARTS; i += 1024) maxblk[i] = 0.0f;
    for (int i = tid; i < 40; i += 1024) { cnt_hi[i] = 0; cnt_mid[i] = 0; }
  }
  int b = blk / 13, pb = blk % 13;
  if (pb == 0) {
    float* ob = out + (size_t)b * 5000;
    for (int i = tid; i < 5000; i += 1024) ob[i] = 0.0f;
  }
  int l = d_pb_l[pb], part = d_pb_part[pb];
  int slice = d_n[l] / d_spl[l];
  int start = d_aoff[l] + part * slice;
  const float4* p4 = (const float4*)(obj + (size_t)b * A_TOTAL + start);
  int s4 = slice >> 2;
  __shared__ int h[4096];
  for (int i = tid; i < 4096; i += 1024) h[i] = 0;
  __syncthreads();
  for (int i = tid; i < s4; i += 1024) {
    float4 v = p4[i];
    atomicAdd(&h[mono(v.x) >> 20], 1);
    atomicAdd(&h[mono(v.y) >> 20], 1);
    atomicAdd(&h[mono(v.z) >> 20], 1);
    atomicAdd(&h[mono(v.w) >> 20], 1);
  }
  __syncthreads();
  int* outp = hist_g + (size_t)blk * 4096;
  for (int i = tid; i < 4096; i += 1024) outp[i] = h[i];
}

// ---------------------------------------------------------------------------
// K2: collect candidates, SPLIT into high (bin > P, guaranteed rank < k by
// threshold construction: suffix(P+1) < k) written at the FRONT of cand_g,
// and mid (bin == P) written at the BACK. Wave-parallel threshold find
// (kept from R5/R6). Wave-aggregated slot allocation; rare-path two ballots.
// ---------------------------------------------------------------------------
__global__ __launch_bounds__(1024) void k_collect(const float* __restrict__ obj,
                                                  const int* __restrict__ hist_g,
                                                  int* __restrict__ cnt_hi,
                                                  int* __restrict__ cnt_mid,
                                                  unsigned long long* __restrict__ cand_g) {
  int blk = blockIdx.x;
  int b = blk / 13, pb = blk % 13;
  int l = d_pb_l[pb], part = d_pb_part[pb];
  int bl = b * NLEV + l;
  const int k = d_k[l];
  int tid = threadIdx.x, lane = tid & 63;
  __shared__ int t[4096];
  __shared__ int grp[256];
  __shared__ unsigned int sP;
  __shared__ __align__(16) unsigned long long lbuf[RCAP];  // 48 KB
  __shared__ int s_hi, s_md, s_bh, s_bm;
  int parts = d_spl[l];
  const int* hb = hist_g + (size_t)(b * 13 + d_bp[l]) * 4096;
  for (int bin = tid; bin < 4096; bin += 1024) {
    int s = 0;
    for (int p = 0; p < parts; ++p) s += hb[p * 4096 + bin];
    t[bin] = s;
  }
  if (tid == 0) { s_hi = 0; s_md = 0; }
  __syncthreads();
  if (tid < 256) {
    int s = 0;
    for (int j = 0; j < 16; ++j) s += t[tid * 16 + j];
    grp[tid] = s;
  }
  __syncthreads();
  if (tid < 64) {  // wave 0: parallel threshold find
    int g0 = grp[4 * tid], g1 = grp[4 * tid + 1];
    int g2 = grp[4 * tid + 2], g3 = grp[4 * tid + 3];
    int q = g0 + g1 + g2 + g3;
    int x = q;  // inclusive suffix-sum over lanes
#pragma unroll
    for (int off = 1; off < 64; off <<= 1) {
      int y = __shfl_down(x, off);
      if (tid + off < 64) x += y;
    }
    int Qn = x - q;
    int best = -1;
    if (x >= k) best = 4 * tid;
    if (g1 + g2 + g3 + Qn >= k) best = 4 * tid + 1;
    if (g2 + g3 + Qn >= k) best = 4 * tid + 2;
    if (g3 + Qn >= k) best = 4 * tid + 3;
#pragma unroll
    for (int off = 1; off < 64; off <<= 1) best = max(best, __shfl_xor(best, off));
    int gstar = best;  // >= 0 (total >= k guaranteed)
    int partl = 0;
    if (4 * tid > gstar) partl += g0;
    if (4 * tid + 1 > gstar) partl += g1;
    if (4 * tid + 2 > gstar) partl += g2;
    if (4 * tid + 3 > gstar) partl += g3;
#pragma unroll
    for (int off = 1; off < 64; off <<= 1) partl += __shfl_xor(partl, off);
    int cum = partl;
    int tb = (tid < 16) ? t[gstar * 16 + tid] : 0;
    int Tx = tb;
#pragma unroll
    for (int off = 1; off < 16; off <<= 1) {
      int y = __shfl_down(Tx, off);
      if (tid + off < 16) Tx += y;
    }
    int bestd = -1;
    if (tid < 16 && cum + Tx >= k) bestd = tid;
#pragma unroll
    for (int off = 1; off < 64; off <<= 1) bestd = max(bestd, __shfl_xor(bestd, off));
    if (tid == 0) sP = (unsigned int)(gstar * 16 + bestd);
  }
  __syncthreads();
  unsigned int P = sP;
  int slice = d_n[l] / parts;
  int start = d_aoff[l] + part * slice;
  const float4* p4 = (const float4*)(obj + (size_t)b * A_TOTAL + start);
  int s4 = slice >> 2;
  int lbase = part * slice;  // level-local base index
  for (int i = tid; i < s4; i += 1024) {
    float4 v = p4[i];
    unsigned int a[4] = {mono(v.x), mono(v.y), mono(v.z), mono(v.w)};
    unsigned int bn[4] = {a[0] >> 20, a[1] >> 20, a[2] >> 20, a[3] >> 20};
    bool any = (bn[0] >= P) | (bn[1] >= P) | (bn[2] >= P) | (bn[3] >= P);
    if (__ballot(any)) {  // wave-uniform; rare
#pragma unroll
      for (int c = 0; c < 4; ++c) {
        bool hi = bn[c] > P, md = bn[c] == P;
        unsigned long long key = ((unsigned long long)a[c] << 32) |
                                 (unsigned int)(~(unsigned int)(lbase + 4 * i + c));
        unsigned long long mbh = __ballot(hi);
        if (mbh) {
          int base;
          if (lane == 0) base = atomicAdd(&s_hi, __popcll(mbh));
          base = __shfl(base, 0);
          if (hi) {
            int slot = base + __popcll(mbh & ((1ull << lane) - 1ull));
            if (slot < RCAP) lbuf[slot] = key;
          }
        }
        unsigned long long mbm = __ballot(md);
        if (mbm) {
          int base;
          if (lane == 0) base = atomicAdd(&s_md, __popcll(mbm));
          base = __shfl(base, 0);
          if (md) {
            int m = base + __popcll(mbm & ((1ull << lane) - 1ull));
            int slot = RCAP - 1 - m;
            if (slot >= 0) lbuf[slot] = key;
          }
        }
      }
    }
  }
  __syncthreads();
  int ch = min(s_hi, RCAP);
  int cm = min(s_md, RCAP - ch);
  if (tid == 0) {
    s_bh = atomicAdd(&cnt_hi[bl], ch);
    s_bm = atomicAdd(&cnt_mid[bl], cm);
  }
  __syncthreads();
  int bh = s_bh, bm = s_bm;
  for (int i = tid; i < ch; i += 1024) {
    int slot = bh + i;
    if (slot < RCAP) cand_g[(size_t)bl * RCAP + slot] = lbuf[i];
  }
  for (int i = tid; i < cm; i += 1024) {
    int gpos = RCAP - bm - cm + i;  // this block's back-region chunk
    if (gpos >= 0) cand_g[(size_t)bl * RCAP + gpos] = lbuf[RCAP - cm + i];
  }
}

// ---------------------------------------------------------------------------
// K3 helper: rank<k -> decode+clip+sigmoid inline; returns max coord (or 0).
// ---------------------------------------------------------------------------
__device__ inline float decode_emit(unsigned long long e, int rank, int b,
                                    int k, int aoff, int bl,
                                    const float* __restrict__ deltas,
                                    const float* __restrict__ anchors,
                                    float* __restrict__ sc0,
                                    float4* __restrict__ box0) {
  if (rank >= k) return 0.0f;
  unsigned int k32 = (unsigned int)(e >> 32);
  unsigned int idx = ~(unsigned int)(e & 0xFFFFFFFFull);
  float o = imono(k32);                       // exact objectness value
  int gidx = aoff + (int)idx;
  const float* dl = deltas + ((size_t)b * A_TOTAL + gidx) * 4;
  const float* an = anchors + (size_t)gidx * 4;
  float a0 = an[0], a1 = an[1], a2 = an[2], a3 = an[3];
  float wa = a2 - a0, ha = a3 - a1;
  float cxa = a0 + 0.5f * wa, cya = a1 + 0.5f * ha;
  float dx = dl[0], dy = dl[1];
  const float CLIPV = 4.135166556742356f;  // log(1000/16)
  float dw = fminf(dl[2], CLIPV), dh = fminf(dl[3], CLIPV);
  float pcx = dx * wa + cxa;               // contract(off): mul+add like numpy
  float pcy = dy * ha + cya;
  float pw = (float)exp((double)dw) * wa;  // correctly-rounded f32 exp
  float ph = (float)exp((double)dh) * ha;
  float x1 = pcx - 0.5f * pw, y1 = pcy - 0.5f * ph;
  float x2 = pcx + 0.5f * pw, y2 = pcy + 0.5f * ph;
  x1 = fminf(fmaxf(x1, 0.0f), 1024.0f);
  x2 = fminf(fmaxf(x2, 0.0f), 1024.0f);
  y1 = fminf(fmaxf(y1, 0.0f), 768.0f);
  y2 = fminf(fmaxf(y2, 0.0f), 768.0f);
  float s = (float)(1.0 / (1.0 + exp(-(double)o)));  // correctly-rounded sigmoid
  bool valid = ((x2 - x1) >= 1.0f) && ((y2 - y1) >= 1.0f) && (s >= 0.0f);
  sc0[bl * 1024 + rank] = valid ? s : -1.0f;
  box0[bl * 1024 + rank] = make_float4(x1, y1, x2, y2);
  return fmaxf(fmaxf(x1, y1), fmaxf(x2, y2));
}

// ---------------------------------------------------------------------------
// K3 v6: split all-pairs rank on LDS-staged keys (R4 structure — measured
// fastest — with group-split work reduction). High keys (bins > P) are all
// greater than every mid key (bin == P), so:
//   rank(high e) = #{high > e}            (A < k guaranteed -> always emitted)
//   rank(mid  e) = A + #{mid > e}         (emit iff < k)
// Compare work A^2 + M^2 instead of (A+M)^2 (~-40%). Groups staged into LDS
// even-padded with 0-sentinels (real keys never 0: low half = ~idx != 0).
// 256 thr x 2 elems, NPARTS=12, broadcast ds_read_b128 streaming as R4.
// ---------------------------------------------------------------------------
__global__ __launch_bounds__(256) void k_rankdec(const unsigned long long* __restrict__ cand_g,
                                                 const int* __restrict__ cnt_hi,
                                                 const int* __restrict__ cnt_mid,
                                                 const float* __restrict__ deltas,
                                                 const float* __restrict__ anchors,
                                                 float* __restrict__ sc0,
                                                 float4* __restrict__ box0,
                                                 float* __restrict__ maxblk) {
  int bl = blockIdx.x / NPARTS, part = blockIdx.x % NPARTS;
  int b = bl / NLEV, l = bl % NLEV;
  const int k = d_k[l], aoff = d_aoff[l];
  int A = min(cnt_hi[bl], RCAP);
  int M = min(cnt_mid[bl], RCAP - A);
  int A2 = (A + 1) & ~1, M2 = (M + 1) & ~1;
  int T = A2 + M2;
  if (part * 512 >= T) return;  // uniform; maxblk[blk] stays 0 (pre-zeroed)
  __shared__ __align__(16) unsigned long long cb[RCAP + 2];
  __shared__ unsigned int s_max;
  int tid = threadIdx.x;
  if (tid == 0) s_max = 0u;
  const unsigned long long* src = cand_g + (size_t)bl * RCAP;
  for (int i = tid; i < A; i += 256) cb[i] = src[i];                 // high
  for (int i = tid; i < M; i += 256) cb[A2 + i] = src[RCAP - M + i]; // mid
  if (tid == 0) {
    if (A & 1) cb[A] = 0ull;        // sentinels: never > any real key,
    if (M & 1) cb[A2 + M] = 0ull;   // never decoded (e==0 check)
  }
  __syncthreads();
  int p0 = part * 512 + tid, p1 = p0 + 256;
  unsigned long long e0 = (p0 < T) ? cb[p0] : 0ull;
  unsigned long long e1 = (p1 < T) ? cb[p1] : 0ull;
  int lo0, n0, ba0, lo1, n1, ba1;
  if (p0 < A2) { lo0 = 0; n0 = A2 >> 1; ba0 = 0; }
  else         { lo0 = A2 >> 1; n0 = M2 >> 1; ba0 = A; }
  if (p1 < A2) { lo1 = 0; n1 = A2 >> 1; ba1 = 0; }
  else         { lo1 = A2 >> 1; n1 = M2 >> 1; ba1 = A; }
  int r0 = 0, r1 = 0;
  const ulonglong2* c2 = (const ulonglong2*)cb;
  if (lo0 == lo1) {  // common case: both elements in the same group
    for (int j = lo0; j < lo0 + n0; ++j) {
      ulonglong2 v = c2[j];
      r0 += (v.x > e0) + (v.y > e0);
      r1 += (v.x > e1) + (v.y > e1);
    }
  } else {
    for (int j = lo0; j < lo0 + n0; ++j) {
      ulonglong2 v = c2[j];
      r0 += (v.x > e0) + (v.y > e0);
    }
    for (int j = lo1; j < lo1 + n1; ++j) {
      ulonglong2 v = c2[j];
      r1 += (v.x > e1) + (v.y > e1);
    }
  }
  float mx = 0.0f;
  if (e0) mx = fmaxf(mx, decode_emit(e0, ba0 + r0, b, k, aoff, bl, deltas, anchors, sc0, box0));
  if (e1) mx = fmaxf(mx, decode_emit(e1, ba1 + r1, b, k, aoff, bl, deltas, anchors, sc0, box0));
#pragma unroll
  for (int s = 1; s < 64; s <<= 1) mx = fmaxf(mx, __shfl_xor(mx, s));
  if ((tid & 63) == 0) atomicMax(&s_max, __float_as_uint(mx));  // 4 atomics/block
  __syncthreads();
  if (tid == 0) maxblk[blockIdx.x] = __uint_as_float(s_max);
}

// ---------------------------------------------------------------------------
// K4: fused compact + mask. Each of the 16 part-blocks per (b,l) redoes the
// one-ballot valid-compaction into LDS (offset-added boxes, topk order);
// part 0 also emits lvlsc/lvlraw/g_V. Then wave w computes suppression word w
// for its 64 rows (word-major masks[bl][word][row]). NMS over valids only is
// exact: invalids start suppressed and are inert.
// ---------------------------------------------------------------------------
__global__ __launch_bounds__(1024) void k_mask(const float* __restrict__ sc0,
                                               const float4* __restrict__ box0,
                                               const float* __restrict__ maxblk,
                                               float* __restrict__ lvlsc,
                                               float4* __restrict__ lvlraw,
                                               int* __restrict__ g_V,
                                               unsigned long long* __restrict__ masks) {
  int blk = blockIdx.x;
  int bl = blk / MSPLIT, part = blk % MSPLIT;
  int b = bl / NLEV, l = bl % NLEV;
  const int k = d_k[l];
  int tid = threadIdx.x, lane = tid & 63, w = tid >> 6;
  __shared__ float4 lbox[1024];
  __shared__ float s_mv;
  __shared__ int s_wcnt[16];
  if (w == 0) {  // reduce maxblk[b*60 .. b*60+60)
    float v = 0.0f;
    for (int i = lane; i < NLEV * NPARTS; i += 64)
      v = fmaxf(v, maxblk[b * (NLEV * NPARTS) + i]);
#pragma unroll
    for (int s = 1; s < 64; s <<= 1) v = fmaxf(v, __shfl_xor(v, s));
    if (lane == 0) s_mv = v;
  }
  bool in = tid < k;
  float s = in ? sc0[bl * 1024 + tid] : -1.0f;
  bool valid = in && (s >= 0.0f);
  unsigned long long mb = __ballot(valid);
  if (lane == 0) s_wcnt[w] = __popcll(mb);
  __syncthreads();
  int pre = 0;
  for (int ww = 0; ww < w; ++ww) pre += s_wcnt[ww];
  int j = pre + __popcll(mb & ((1ull << lane) - 1ull));
  int V = 0;
  for (int ww = 0; ww < 16; ++ww) V += s_wcnt[ww];
  float off = (float)l * (s_mv + 1.0f);
  if (valid) {
    float4 bx = box0[bl * 1024 + tid];
    lbox[j] = make_float4(bx.x + off, bx.y + off, bx.z + off, bx.w + off);
    if (part == 0) {
      lvlsc[bl * 1024 + j] = s;
      lvlraw[bl * 1024 + j] = bx;
    }
  }
  if (part == 0 && tid == 0) g_V[bl] = V;
  __syncthreads();
  int row0 = part * 64;
  if (row0 >= V) return;                      // block-uniform; barriers done
  int i = row0 + lane;                        // my row
  if (i >= V) return;                         // per-lane exit after last barrier
  float4 bb = lbox[i];
  float ba = (bb.z - bb.x) * (bb.w - bb.y);
  unsigned long long bits = 0ull;
  int jbase = w * 64;
  if (jbase + 63 > i && jbase < V) {
    int jhi = min(64, V - jbase);
    for (int jo = 0; jo < jhi; ++jo) {        // jj uniform across the wave
      int jj = jbase + jo;
      float4 cb = lbox[jj];
      float ca = (cb.z - cb.x) * (cb.w - cb.y);
      float xx1 = fmaxf(bb.x, cb.x), yy1 = fmaxf(bb.y, cb.y);
      float xx2 = fminf(bb.z, cb.z), yy2 = fminf(bb.w, cb.w);
      float wd = fmaxf(xx2 - xx1, 0.0f), ht = fmaxf(yy2 - yy1, 0.0f);
      float inter = wd * ht;
      float denom = fmaxf(ba + ca - inter, 1e-9f);
      if ((jj > i) && ((double)inter >= TM_IOU * (double)denom)) bits |= (1ull << jo);
    }
  }
  masks[((size_t)bl * 16 + w) * 1024 + i] = bits;  // coalesced across lanes
}

// ---------------------------------------------------------------------------
// K5: serial bitmask scan over V valids, one 16-wave block per (b,l) (R4
// version — the 1-wave variant measured 61.8 µs from zero TLP). val loads
// software-pipelined one chunk ahead. Ends with ballot-compaction of kept
// entries to ksc_g/kj_g/K_g (topk order preserved -> descending scores).
// ---------------------------------------------------------------------------
__global__ __launch_bounds__(1024) void k_scan(const unsigned long long* __restrict__ masks,
                                               const int* __restrict__ g_V,
                                               const float* __restrict__ lvlsc,
                                               float* __restrict__ ksc_g,
                                               int* __restrict__ kj_g,
                                               int* __restrict__ K_g) {
  int bl = blockIdx.x;
  int tid = threadIdx.x, lane = tid & 63, w = tid >> 6;
  int V = g_V[bl];
  const int nch = (V + 63) / 64;
  const unsigned long long* M = masks + (size_t)bl * 16 * 1024;
  __shared__ unsigned long long s_remv[16];
  __shared__ unsigned long long s_D[2][72];   // 64 + 8 pad (scan prefetch)
  __shared__ unsigned long long s_dw;
  __shared__ int s_wcnt[16];
  if (tid < 16) s_remv[tid] = ~0ull;          // words beyond nch: nothing kept
  int base_w = w * 64;
  unsigned long long init_w;
  if (V <= base_w) init_w = ~0ull;
  else if (V >= base_w + 64) init_w = 0ull;
  else init_w = (~0ull) << (V - base_w);
  if (w == 0 && nch > 0) s_D[0][lane] = (lane < V) ? M[lane] : 0ull;
  if (tid < 8) { s_D[0][64 + tid] = 0ull; s_D[1][64 + tid] = 0ull; }
  unsigned long long acc = 0ull;
  unsigned long long val_next = 0ull;
  if (w > 0 && w < nch && lane < V) val_next = M[(size_t)w * 1024 + lane];
  __syncthreads();

  for (int c = 0; c < nch; ++c) {
    unsigned long long val = val_next;
    val_next = 0ull;                          // prefetch val for chunk c+1
    int rn = 64 * (c + 1) + lane;
    if (w > c + 1 && w < nch && rn < V) val_next = M[(size_t)w * 1024 + rn];
    if (w == c) {
      unsigned long long red = acc;
#pragma unroll
      for (int s = 1; s < 64; s <<= 1) red |= __shfl_xor(red, s);
      unsigned long long dw = init_w | red;
      const unsigned long long* D = s_D[c & 1];
      unsigned long long pb[8];
#pragma unroll
      for (int u = 0; u < 8; ++u) pb[u] = D[u];
#pragma unroll
      for (int g = 0; g < 8; ++g) {
#pragma unroll
        for (int u = 0; u < 8; ++u) {
          int jj = g * 8 + u;
          if (!((dw >> jj) & 1ull)) dw |= pb[u];
          pb[u] = D[jj + 8];  // decision-independent prefetch (padded)
        }
      }
      if (lane == 0) { s_dw = dw; s_remv[c] = dw; }
    }
    if (w == c + 1 && w < nch) {
      int rr = 64 * (c + 1) + lane;
      s_D[(c + 1) & 1][lane] = (rr < V) ? M[(size_t)(c + 1) * 1024 + rr] : 0ull;
    }
    __syncthreads();
    if (w > c && w < nch) {
      unsigned long long kept = ~s_dw;
      if ((kept >> lane) & 1ull) acc |= val;
    }
    __syncthreads();  // protect s_dw before next chunk overwrites it
  }

  // ---- fused compaction of kept entries (topk order preserved) ----
  unsigned long long kb = ~s_remv[w];         // rows >= V stay suppressed
  bool kept = ((kb >> lane) & 1ull) != 0ull;
  unsigned long long mb = __ballot(kept);
  if (lane == 0) s_wcnt[w] = __popcll(mb);
  __syncthreads();
  int pre = 0;
  for (int ww = 0; ww < w; ++ww) pre += s_wcnt[ww];
  int r = pre + __popcll(mb & ((1ull << lane) - 1ull));
  if (kept) {
    ksc_g[bl * 1024 + r] = lvlsc[bl * 1024 + tid];
    kj_g[bl * 1024 + r] = tid;
  }
  if (tid == 0) {
    int t = 0;
    for (int ww = 0; ww < 16; ++ww) t += s_wcnt[ww];
    K_g[bl] = t;
  }
}

// ---------------------------------------------------------------------------
// K6: merge. One block per (b,l) — 40-way parallel. Loads the batch's 5
// compacted score lists into LDS, computes global output rank only for its
// own level's kept entries (5-way stable merge: cnt_ge for earlier levels /
// cnt_gt for later), scatters rows with rank<1000. Zeros pre-written by
// k_hist; each rank<1000 cell written by exactly one (level, i).
// ---------------------------------------------------------------------------
__global__ __launch_bounds__(1024) void k_merge(const float* __restrict__ ksc_g,
                                                const int* __restrict__ kj_g,
                                                const int* __restrict__ K_g,
                                                const float4* __restrict__ lvlraw,
                                                float* __restrict__ out) {
  int blk = blockIdx.x;
  int b = blk / NLEV, l = blk % NLEV;
  int tid = threadIdx.x;
  __shared__ float ksc[NLEV * 1024];  // 20 KB
  __shared__ int sK[NLEV];
  if (tid < NLEV) sK[tid] = K_g[b * NLEV + tid];
  __syncthreads();
  int K[NLEV];
  for (int l2 = 0; l2 < NLEV; ++l2) K[l2] = sK[l2];
  for (int l2 = 0; l2 < NLEV; ++l2) {
    for (int i = tid; i < K[l2]; i += 1024)
      ksc[l2 * 1024 + i] = ksc_g[(size_t)(b * NLEV + l2) * 1024 + i];
  }
  __syncthreads();
  if (tid < K[l]) {
    float s = ksc[l * 1024 + tid];
    int rank = tid;  // within-level kept ties: earlier topk rank first
    for (int l2 = 0; l2 < NLEV; ++l2) {
      if (l2 == l) continue;
      const float* A = ksc + l2 * 1024;
      rank += (l2 < l) ? cnt_ge(A, K[l2], s) : cnt_gt(A, K[l2], s);
    }
    if (rank < 1000) {
      int j = kj_g[(size_t)(b * NLEV + l) * 1024 + tid];
      float4 bx = lvlraw[(size_t)(b * NLEV + l) * 1024 + j];
      float* op = out + (size_t)b * 5000 + (size_t)rank * 5;
      op[0] = bx.x; op[1] = bx.y; op[2] = bx.z; op[3] = bx.w; op[4] = s;
    }
  }
}

extern "C" void kernel_launch(void* const* d_in, const int* in_sizes, int n_in,
                              void* d_out, int out_size, void* d_ws, size_t ws_size,
                              hipStream_t stream) {
  const float* obj     = (const float*)d_in[0];
  const float* deltas  = (const float*)d_in[1];
  const float* anchors = (const float*)d_in[2];
  float* out = (float*)d_out;

  // workspace layout (~11 MB; descending alignment order)
  char* p = (char*)d_ws;
  float4* box0   = (float4*)p; p += (size_t)40 * 1024 * sizeof(float4);
  float4* lvlraw = (float4*)p; p += (size_t)40 * 1024 * sizeof(float4);
  unsigned long long* cand_g = (unsigned long long*)p; p += (size_t)40 * RCAP * 8;
  unsigned long long* masks  = (unsigned long long*)p; p += (size_t)40 * 16 * 1024 * 8;
  int*   hist_g = (int*)p;   p += (size_t)104 * 4096 * 4;
  int*   cnt_hi = (int*)p;   p += 40 * 4;
  int*   cnt_mid= (int*)p;   p += 40 * 4;
  float* maxblk = (float*)p; p += (size_t)40 * NPARTS * 4;
  float* sc0    = (float*)p; p += (size_t)40 * 1024 * 4;
  float* lvlsc  = (float*)p; p += (size_t)40 * 1024 * 4;
  int*   g_V    = (int*)p;   p += 40 * 4;
  float* ksc_g  = (float*)p; p += (size_t)40 * 1024 * 4;
  int*   kj_g   = (int*)p;   p += (size_t)40 * 1024 * 4;
  int*   K_g    = (int*)p;   p += 40 * 4;

  hipLaunchKernelGGL(k_hist, dim3(BATCH * 13), dim3(1024), 0, stream,
                     obj, hist_g, cnt_hi, cnt_mid, maxblk, out);
  hipLaunchKernelGGL(k_collect, dim3(BATCH * 13), dim3(1024), 0, stream,
                     obj, hist_g, cnt_hi, cnt_mid, cand_g);
  hipLaunchKernelGGL(k_rankdec, dim3(BATCH * NLEV * NPARTS), dim3(256), 0, stream,
                     cand_g, cnt_hi, cnt_mid, deltas, anchors, sc0, box0, maxblk);
  hipLaunchKernelGGL(k_mask, dim3(BATCH * NLEV * MSPLIT), dim3(1024), 0, stream,
                     sc0, box0, maxblk, lvlsc, lvlraw, g_V, masks);
  hipLaunchKernelGGL(k_scan, dim3(BATCH * NLEV), dim3(1024), 0, stream,
                     masks, g_V, lvlsc, ksc_g, kj_g, K_g);
  hipLaunchKernelGGL(k_merge, dim3(BATCH * NLEV), dim3(1024), 0, stream,
                     ksc_g, kj_g, K_g, lvlraw, out);
}

// Round 8
// 201.290 us; speedup vs baseline: 1.2509x; 1.2509x over previous
//
#include <hip/hip_runtime.h>
#include <math.h>

#pragma clang fp contract(off)

#define A_TOTAL 196416
#define BATCH 8
#define KTOT 4576
#define NLEV 5
#define MSPLIT 16
#define RCAP 6144        // per-(b,l) candidate cap (typical cnt ~1.2k)
#define NPARTS 12        // rank parts: 12*512 == RCAP (256-thr blocks, 2 elems/thr)

static __device__ const int d_aoff[NLEV] = {0, 147456, 184320, 193536, 195840};
static __device__ const int d_n[NLEV]    = {147456, 36864, 9216, 2304, 576};
static __device__ const int d_k[NLEV]    = {1000, 1000, 1000, 1000, 576};
// histogram slice-splits per level (13 parts per batch)
static __device__ const int d_spl[NLEV]  = {8, 2, 1, 1, 1};
static __device__ const int d_bp[NLEV]   = {0, 8, 10, 11, 12};
static __device__ const int d_pb_l[13]    = {0,0,0,0,0,0,0,0,1,1,2,3,4};
static __device__ const int d_pb_part[13] = {0,1,2,3,4,5,6,7,0,1,0,0,0};

// Exact-equivalence constant for "RN(inter/denom) > 0.7f":
//   RN(q) > 0.7f  <=>  q >= midpoint(0.7f, nextafter(0.7f))  <=>
//   (double)inter >= TM_IOU * (double)denom  exactly (<=49 sig bits).
#define TM_IOU (0.699999988079071044921875 + 0x1p-25)

// monotone map: f32 -> u32 preserving order (no NaNs in this data); invertible
__device__ inline unsigned int mono(float f) {
  unsigned int u = __float_as_uint(f);
  return (u & 0x80000000u) ? ~u : (u | 0x80000000u);
}
__device__ inline float imono(unsigned int m) {
  return __uint_as_float((m & 0x80000000u) ? (m & 0x7FFFFFFFu) : ~m);
}

// binary searches on a descending-sorted array
__device__ inline int cnt_gt(const float* A, int n, float s) {  // #{A[i] > s}
  int lo = 0, hi = n;
  while (lo < hi) { int mid = (lo + hi) >> 1; if (A[mid] > s) lo = mid + 1; else hi = mid; }
  return lo;
}
__device__ inline int cnt_ge(const float* A, int n, float s) {  // #{A[i] >= s}
  int lo = 0, hi = n;
  while (lo < hi) { int mid = (lo + hi) >> 1; if (A[mid] >= s) lo = mid + 1; else hi = mid; }
  return lo;
}

// ---------------------------------------------------------------------------
// K1: per-(b,l,part) private 4096-bin histogram of mono(obj) top-12 bits.
// Block 0 zero-inits cnt_g, maxblk, done; the pb==0 block of each batch also
// zero-fills that batch's output slice (removes the zero-fill from the tail).
// ---------------------------------------------------------------------------
__global__ __launch_bounds__(1024) void k_hist(const float* __restrict__ obj,
                                               int* __restrict__ hist_g,
                                               int* __restrict__ cnt_g,
                                               float* __restrict__ maxblk,
                                               int* __restrict__ done,
                                               float* __restrict__ out) {
  int blk = blockIdx.x;
  int tid = threadIdx.x;
  if (blk == 0) {
    for (int i = tid; i < 40 * NPARTS; i += 1024) maxblk[i] = 0.0f;
    for (int i = tid; i < 40; i += 1024) cnt_g[i] = 0;
    if (tid < BATCH) done[tid] = 0;
  }
  int b = blk / 13, pb = blk % 13;
  if (pb == 0) {
    float* ob = out + (size_t)b * 5000;
    for (int i = tid; i < 5000; i += 1024) ob[i] = 0.0f;
  }
  int l = d_pb_l[pb], part = d_pb_part[pb];
  int slice = d_n[l] / d_spl[l];
  int start = d_aoff[l] + part * slice;
  const float4* p4 = (const float4*)(obj + (size_t)b * A_TOTAL + start);
  int s4 = slice >> 2;
  __shared__ int h[4096];
  for (int i = tid; i < 4096; i += 1024) h[i] = 0;
  __syncthreads();
  for (int i = tid; i < s4; i += 1024) {
    float4 v = p4[i];
    atomicAdd(&h[mono(v.x) >> 20], 1);
    atomicAdd(&h[mono(v.y) >> 20], 1);
    atomicAdd(&h[mono(v.z) >> 20], 1);
    atomicAdd(&h[mono(v.w) >> 20], 1);
  }
  __syncthreads();
  int* outp = hist_g + (size_t)blk * 4096;
  for (int i = tid; i < 4096; i += 1024) outp[i] = h[i];
}

// ---------------------------------------------------------------------------
// K2: collect candidates (R4 data layout: single cand_g + cnt_g). Threshold
// derivation is WAVE-PARALLEL (R5, verified −12 µs). Wave-aggregated slot
// allocation; fast path: one combined ballot per float4 group.
// ---------------------------------------------------------------------------
__global__ __launch_bounds__(1024) void k_collect(const float* __restrict__ obj,
                                                  const int* __restrict__ hist_g,
                                                  int* __restrict__ cnt_g,
                                                  unsigned long long* __restrict__ cand_g) {
  int blk = blockIdx.x;
  int b = blk / 13, pb = blk % 13;
  int l = d_pb_l[pb], part = d_pb_part[pb];
  int bl = b * NLEV + l;
  const int k = d_k[l];
  int tid = threadIdx.x, lane = tid & 63;
  __shared__ int t[4096];
  __shared__ int grp[256];
  __shared__ unsigned int sP;
  __shared__ __align__(16) unsigned long long lbuf[RCAP];  // 48 KB
  __shared__ int s_cnt, s_base;
  int parts = d_spl[l];
  const int* hb = hist_g + (size_t)(b * 13 + d_bp[l]) * 4096;
  for (int bin = tid; bin < 4096; bin += 1024) {
    int s = 0;
    for (int p = 0; p < parts; ++p) s += hb[p * 4096 + bin];
    t[bin] = s;
  }
  if (tid == 0) s_cnt = 0;
  __syncthreads();
  if (tid < 256) {
    int s = 0;
    for (int j = 0; j < 16; ++j) s += t[tid * 16 + j];
    grp[tid] = s;
  }
  __syncthreads();
  if (tid < 64) {  // wave 0: parallel threshold find
    int g0 = grp[4 * tid], g1 = grp[4 * tid + 1];
    int g2 = grp[4 * tid + 2], g3 = grp[4 * tid + 3];
    int q = g0 + g1 + g2 + g3;
    int x = q;  // inclusive suffix-sum over lanes
#pragma unroll
    for (int off = 1; off < 64; off <<= 1) {
      int y = __shfl_down(x, off);
      if (tid + off < 64) x += y;
    }
    int Qn = x - q;
    int best = -1;
    if (x >= k) best = 4 * tid;
    if (g1 + g2 + g3 + Qn >= k) best = 4 * tid + 1;
    if (g2 + g3 + Qn >= k) best = 4 * tid + 2;
    if (g3 + Qn >= k) best = 4 * tid + 3;
#pragma unroll
    for (int off = 1; off < 64; off <<= 1) best = max(best, __shfl_xor(best, off));
    int gstar = best;  // >= 0 (total >= k guaranteed)
    int partl = 0;
    if (4 * tid > gstar) partl += g0;
    if (4 * tid + 1 > gstar) partl += g1;
    if (4 * tid + 2 > gstar) partl += g2;
    if (4 * tid + 3 > gstar) partl += g3;
#pragma unroll
    for (int off = 1; off < 64; off <<= 1) partl += __shfl_xor(partl, off);
    int cum = partl;
    int tb = (tid < 16) ? t[gstar * 16 + tid] : 0;
    int Tx = tb;
#pragma unroll
    for (int off = 1; off < 16; off <<= 1) {
      int y = __shfl_down(Tx, off);
      if (tid + off < 16) Tx += y;
    }
    int bestd = -1;
    if (tid < 16 && cum + Tx >= k) bestd = tid;
#pragma unroll
    for (int off = 1; off < 64; off <<= 1) bestd = max(bestd, __shfl_xor(bestd, off));
    if (tid == 0) sP = (unsigned int)(gstar * 16 + bestd);
  }
  __syncthreads();
  unsigned int P = sP;  // take keys with (key>>20) >= P; count >= k guaranteed
  int slice = d_n[l] / parts;
  int start = d_aoff[l] + part * slice;
  const float4* p4 = (const float4*)(obj + (size_t)b * A_TOTAL + start);
  int s4 = slice >> 2;
  int lbase = part * slice;  // level-local base index
  for (int i = tid; i < s4; i += 1024) {
    float4 v = p4[i];
    unsigned int a[4] = {mono(v.x), mono(v.y), mono(v.z), mono(v.w)};
    bool q0 = (a[0] >> 20) >= P, q1 = (a[1] >> 20) >= P;
    bool q2 = (a[2] >> 20) >= P, q3 = (a[3] >> 20) >= P;
    if (__ballot(q0 | q1 | q2 | q3)) {  // wave-uniform; rare
      bool qs[4] = {q0, q1, q2, q3};
#pragma unroll
      for (int c = 0; c < 4; ++c) {
        unsigned long long mb = __ballot(qs[c]);
        if (mb) {
          int base;
          if (lane == 0) base = atomicAdd(&s_cnt, __popcll(mb));
          base = __shfl(base, 0);
          if (qs[c]) {
            int slot = base + __popcll(mb & ((1ull << lane) - 1ull));
            if (slot < RCAP) {
              int idx = lbase + 4 * i + c;
              lbuf[slot] = ((unsigned long long)a[c] << 32) |
                           (unsigned int)(~(unsigned int)idx);
            }
          }
        }
      }
    }
  }
  __syncthreads();
  int cnt = min(s_cnt, RCAP);
  if (tid == 0) s_base = atomicAdd(&cnt_g[bl], cnt);  // one global atomic/block
  __syncthreads();
  int base = s_base;
  for (int i = tid; i < cnt; i += 1024) {
    int slot = base + i;
    if (slot < RCAP) cand_g[(size_t)bl * RCAP + slot] = lbuf[i];
  }
}

// ---------------------------------------------------------------------------
// K3 helper: rank<k -> decode+clip+sigmoid inline; returns max coord (or 0).
// ---------------------------------------------------------------------------
__device__ inline float decode_emit(unsigned long long e, int rank, int b,
                                    int k, int aoff, int bl,
                                    const float* __restrict__ deltas,
                                    const float* __restrict__ anchors,
                                    float* __restrict__ sc0,
                                    float4* __restrict__ box0) {
  if (rank >= k) return 0.0f;
  unsigned int k32 = (unsigned int)(e >> 32);
  unsigned int idx = ~(unsigned int)(e & 0xFFFFFFFFull);
  float o = imono(k32);                       // exact objectness value
  int gidx = aoff + (int)idx;
  const float* dl = deltas + ((size_t)b * A_TOTAL + gidx) * 4;
  const float* an = anchors + (size_t)gidx * 4;
  float a0 = an[0], a1 = an[1], a2 = an[2], a3 = an[3];
  float wa = a2 - a0, ha = a3 - a1;
  float cxa = a0 + 0.5f * wa, cya = a1 + 0.5f * ha;
  float dx = dl[0], dy = dl[1];
  const float CLIPV = 4.135166556742356f;  // log(1000/16)
  float dw = fminf(dl[2], CLIPV), dh = fminf(dl[3], CLIPV);
  float pcx = dx * wa + cxa;               // contract(off): mul+add like numpy
  float pcy = dy * ha + cya;
  float pw = (float)exp((double)dw) * wa;  // correctly-rounded f32 exp
  float ph = (float)exp((double)dh) * ha;
  float x1 = pcx - 0.5f * pw, y1 = pcy - 0.5f * ph;
  float x2 = pcx + 0.5f * pw, y2 = pcy + 0.5f * ph;
  x1 = fminf(fmaxf(x1, 0.0f), 1024.0f);
  x2 = fminf(fmaxf(x2, 0.0f), 1024.0f);
  y1 = fminf(fmaxf(y1, 0.0f), 768.0f);
  y2 = fminf(fmaxf(y2, 0.0f), 768.0f);
  float s = (float)(1.0 / (1.0 + exp(-(double)o)));  // correctly-rounded sigmoid
  bool valid = ((x2 - x1) >= 1.0f) && ((y2 - y1) >= 1.0f) && (s >= 0.0f);
  sc0[bl * 1024 + rank] = valid ? s : -1.0f;
  box0[bl * 1024 + rank] = make_float4(x1, y1, x2, y2);
  return fmaxf(fmaxf(x1, y1), fmaxf(x2, y2));
}

// ---------------------------------------------------------------------------
// K3: rank candidates + inline decode — u64 all-pairs on LDS-staged keys,
// EXACT R4 form (empirically fastest across R2/R5/R6/R7 alternatives: the
// uniform-trip-count loop + LDS broadcast stream is what the compiler
// pipelines best). 256 thr x 2 elems, NPARTS=12.
// ---------------------------------------------------------------------------
__global__ __launch_bounds__(256) void k_rankdec(const unsigned long long* __restrict__ cand_g,
                                                 const int* __restrict__ cnt_g,
                                                 const float* __restrict__ deltas,
                                                 const float* __restrict__ anchors,
                                                 float* __restrict__ sc0,
                                                 float4* __restrict__ box0,
                                                 float* __restrict__ maxblk) {
  int bl = blockIdx.x / NPARTS, part = blockIdx.x % NPARTS;
  int b = bl / NLEV, l = bl % NLEV;
  const int k = d_k[l], aoff = d_aoff[l];
  int cnt = min(cnt_g[bl], RCAP);
  if (part * 512 >= cnt) return;  // uniform; maxblk[blk] stays 0 (pre-zeroed)
  __shared__ __align__(16) unsigned long long cb[RCAP];  // 48 KB
  __shared__ unsigned int s_max;
  int tid = threadIdx.x;
  if (tid == 0) s_max = 0u;
  const unsigned long long* src = cand_g + (size_t)bl * RCAP;
  {  // vectorized staging (16B): src is 16B-aligned (bl*RCAP*8, RCAP even)
    const ulonglong2* s2 = (const ulonglong2*)src;
    ulonglong2* d2 = (ulonglong2*)cb;
    int n2 = cnt >> 1;
    for (int i = tid; i < n2; i += 256) d2[i] = s2[i];
    if ((cnt & 1) && tid == 0) cb[cnt - 1] = src[cnt - 1];
  }
  __syncthreads();
  int i0 = part * 512 + tid, i1 = i0 + 256;
  unsigned long long e0 = ~0ull, e1 = ~0ull;  // sentinels; emission gated below
  if (i0 < cnt) e0 = cb[i0];
  if (i1 < cnt) e1 = cb[i1];
  int r0 = 0, r1 = 0;
  int nc2 = cnt >> 1;
  const ulonglong2* c2 = (const ulonglong2*)cb;
  for (int j = 0; j < nc2; ++j) {
    ulonglong2 v = c2[j];
    r0 += (v.x > e0) + (v.y > e0);
    r1 += (v.x > e1) + (v.y > e1);
  }
  if (cnt & 1) {
    unsigned long long v = cb[cnt - 1];
    r0 += (v > e0);
    r1 += (v > e1);
  }
  float mx = 0.0f;
  if (i0 < cnt) mx = fmaxf(mx, decode_emit(e0, r0, b, k, aoff, bl, deltas, anchors, sc0, box0));
  if (i1 < cnt) mx = fmaxf(mx, decode_emit(e1, r1, b, k, aoff, bl, deltas, anchors, sc0, box0));
#pragma unroll
  for (int s = 1; s < 64; s <<= 1) mx = fmaxf(mx, __shfl_xor(mx, s));
  if ((tid & 63) == 0) atomicMax(&s_max, __float_as_uint(mx));  // 4 atomics/block
  __syncthreads();
  if (tid == 0) maxblk[blockIdx.x] = __uint_as_float(s_max);
}

// ---------------------------------------------------------------------------
// K4: fused compact + mask. Each of the 16 part-blocks per (b,l) redoes the
// one-ballot valid-compaction into LDS (offset-added boxes, topk order);
// part 0 also emits lvlsc/lvlraw/g_V. Then wave w computes suppression word w
// for its 64 rows (word-major masks[bl][word][row]). NMS over valids only is
// exact: invalids start suppressed and are inert.
// ---------------------------------------------------------------------------
__global__ __launch_bounds__(1024) void k_mask(const float* __restrict__ sc0,
                                               const float4* __restrict__ box0,
                                               const float* __restrict__ maxblk,
                                               float* __restrict__ lvlsc,
                                               float4* __restrict__ lvlraw,
                                               int* __restrict__ g_V,
                                               unsigned long long* __restrict__ masks) {
  int blk = blockIdx.x;
  int bl = blk / MSPLIT, part = blk % MSPLIT;
  int b = bl / NLEV, l = bl % NLEV;
  const int k = d_k[l];
  int tid = threadIdx.x, lane = tid & 63, w = tid >> 6;
  __shared__ float4 lbox[1024];
  __shared__ float s_mv;
  __shared__ int s_wcnt[16];
  if (w == 0) {  // reduce maxblk[b*60 .. b*60+60)
    float v = 0.0f;
    for (int i = lane; i < NLEV * NPARTS; i += 64)
      v = fmaxf(v, maxblk[b * (NLEV * NPARTS) + i]);
#pragma unroll
    for (int s = 1; s < 64; s <<= 1) v = fmaxf(v, __shfl_xor(v, s));
    if (lane == 0) s_mv = v;
  }
  bool in = tid < k;
  float s = in ? sc0[bl * 1024 + tid] : -1.0f;
  bool valid = in && (s >= 0.0f);
  unsigned long long mb = __ballot(valid);
  if (lane == 0) s_wcnt[w] = __popcll(mb);
  __syncthreads();
  int pre = 0;
  for (int ww = 0; ww < w; ++ww) pre += s_wcnt[ww];
  int j = pre + __popcll(mb & ((1ull << lane) - 1ull));
  int V = 0;
  for (int ww = 0; ww < 16; ++ww) V += s_wcnt[ww];
  float off = (float)l * (s_mv + 1.0f);
  if (valid) {
    float4 bx = box0[bl * 1024 + tid];
    lbox[j] = make_float4(bx.x + off, bx.y + off, bx.z + off, bx.w + off);
    if (part == 0) {
      lvlsc[bl * 1024 + j] = s;
      lvlraw[bl * 1024 + j] = bx;
    }
  }
  if (part == 0 && tid == 0) g_V[bl] = V;
  __syncthreads();
  int row0 = part * 64;
  if (row0 >= V) return;                      // block-uniform; barriers done
  int i = row0 + lane;                        // my row
  if (i >= V) return;                         // per-lane exit after last barrier
  float4 bb = lbox[i];
  float ba = (bb.z - bb.x) * (bb.w - bb.y);
  unsigned long long bits = 0ull;
  int jbase = w * 64;
  if (jbase + 63 > i && jbase < V) {
    int jhi = min(64, V - jbase);
    for (int jo = 0; jo < jhi; ++jo) {        // jj uniform across the wave
      int jj = jbase + jo;
      float4 cb = lbox[jj];
      float ca = (cb.z - cb.x) * (cb.w - cb.y);
      float xx1 = fmaxf(bb.x, cb.x), yy1 = fmaxf(bb.y, cb.y);
      float xx2 = fminf(bb.z, cb.z), yy2 = fminf(bb.w, cb.w);
      float wd = fmaxf(xx2 - xx1, 0.0f), ht = fmaxf(yy2 - yy1, 0.0f);
      float inter = wd * ht;
      float denom = fmaxf(ba + ca - inter, 1e-9f);
      if ((jj > i) && ((double)inter >= TM_IOU * (double)denom)) bits |= (1ull << jo);
    }
  }
  masks[((size_t)bl * 16 + w) * 1024 + i] = bits;  // coalesced across lanes
}

// ---------------------------------------------------------------------------
// K5 (fused scan + merge): one 16-wave block per (b,l). Scan phase = R4
// k_scan (software-pipelined val loads). Compaction publishes ksc_g/K_g via
// atomicExch (RMW -> coherent point, XCD-safe); kj_g plain (self-read only).
// Release: __threadfence + done[b] atomicAdd. Then every block spins on
// done[b]==NLEV and merges ITS OWN level (keeps R4's 40-way merge
// parallelism), reading cross-block ksc/K via RMW reads (atomicAdd 0).
// All 40 blocks trivially co-resident on 256 CUs -> no deadlock.
// ---------------------------------------------------------------------------
__global__ __launch_bounds__(1024) void k_tail(const unsigned long long* __restrict__ masks,
                                               const int* __restrict__ g_V,
                                               const float* __restrict__ lvlsc,
                                               float* __restrict__ ksc_g,
                                               int* __restrict__ kj_g,
                                               int* __restrict__ K_g,
                                               int* __restrict__ done,
                                               const float4* __restrict__ lvlraw,
                                               float* __restrict__ out) {
  int bl = blockIdx.x;
  int b = bl / NLEV, l = bl % NLEV;
  int tid = threadIdx.x, lane = tid & 63, w = tid >> 6;
  int V = g_V[bl];
  const int nch = (V + 63) / 64;
  const unsigned long long* M = masks + (size_t)bl * 16 * 1024;
  __shared__ unsigned long long s_remv[16];
  __shared__ unsigned long long s_D[2][72];   // 64 + 8 pad (scan prefetch)
  __shared__ unsigned long long s_dw;
  __shared__ int s_wcnt[16];
  if (tid < 16) s_remv[tid] = ~0ull;          // words beyond nch: nothing kept
  int base_w = w * 64;
  unsigned long long init_w;
  if (V <= base_w) init_w = ~0ull;
  else if (V >= base_w + 64) init_w = 0ull;
  else init_w = (~0ull) << (V - base_w);
  if (w == 0 && nch > 0) s_D[0][lane] = (lane < V) ? M[lane] : 0ull;
  if (tid < 8) { s_D[0][64 + tid] = 0ull; s_D[1][64 + tid] = 0ull; }
  unsigned long long acc = 0ull;
  unsigned long long val_next = 0ull;
  if (w > 0 && w < nch && lane < V) val_next = M[(size_t)w * 1024 + lane];
  __syncthreads();

  for (int c = 0; c < nch; ++c) {
    unsigned long long val = val_next;
    val_next = 0ull;                          // prefetch val for chunk c+1
    int rn = 64 * (c + 1) + lane;
    if (w > c + 1 && w < nch && rn < V) val_next = M[(size_t)w * 1024 + rn];
    if (w == c) {
      unsigned long long red = acc;
#pragma unroll
      for (int s = 1; s < 64; s <<= 1) red |= __shfl_xor(red, s);
      unsigned long long dw = init_w | red;
      const unsigned long long* D = s_D[c & 1];
      unsigned long long pb[8];
#pragma unroll
      for (int u = 0; u < 8; ++u) pb[u] = D[u];
#pragma unroll
      for (int g = 0; g < 8; ++g) {
#pragma unroll
        for (int u = 0; u < 8; ++u) {
          int jj = g * 8 + u;
          if (!((dw >> jj) & 1ull)) dw |= pb[u];
          pb[u] = D[jj + 8];  // decision-independent prefetch (padded)
        }
      }
      if (lane == 0) { s_dw = dw; s_remv[c] = dw; }
    }
    if (w == c + 1 && w < nch) {
      int rr = 64 * (c + 1) + lane;
      s_D[(c + 1) & 1][lane] = (rr < V) ? M[(size_t)(c + 1) * 1024 + rr] : 0ull;
    }
    __syncthreads();
    if (w > c && w < nch) {
      unsigned long long kept = ~s_dw;
      if ((kept >> lane) & 1ull) acc |= val;
    }
    __syncthreads();  // protect s_dw before next chunk overwrites it
  }

  // ---- compaction of kept entries; publish at the coherent point ----
  unsigned long long kb = ~s_remv[w];         // rows >= V stay suppressed
  bool kept = ((kb >> lane) & 1ull) != 0ull;
  unsigned long long mb = __ballot(kept);
  if (lane == 0) s_wcnt[w] = __popcll(mb);
  __syncthreads();
  int pre = 0;
  for (int ww = 0; ww < w; ++ww) pre += s_wcnt[ww];
  int r = pre + __popcll(mb & ((1ull << lane) - 1ull));
  if (kept) {
    atomicExch(&ksc_g[bl * 1024 + r], lvlsc[bl * 1024 + tid]);  // RMW publish
    kj_g[bl * 1024 + r] = tid;                                  // self-read only
  }
  int Kown = 0;
  for (int ww = 0; ww < 16; ++ww) Kown += s_wcnt[ww];
  if (tid == 0) atomicExch(&K_g[bl], Kown);
  __threadfence();
  __syncthreads();
  if (tid == 0) atomicAdd(&done[b], 1);

  // ---- merge phase (every block handles its own level; 40-way parallel) ----
  if (tid == 0) {
    while (atomicAdd(&done[b], 0) < NLEV) __builtin_amdgcn_s_sleep(8);
  }
  __syncthreads();
  __shared__ float ksc[NLEV * 1024];  // 20 KB
  __shared__ int sK[NLEV];
  if (tid < NLEV) sK[tid] = atomicAdd(&K_g[b * NLEV + tid], 0);  // RMW read
  __syncthreads();
  int K[NLEV];
  for (int l2 = 0; l2 < NLEV; ++l2) K[l2] = sK[l2];
  for (int l2 = 0; l2 < NLEV; ++l2) {
    float* dst = ksc + l2 * 1024;
    if (l2 == l) {  // own level: self-written, plain read OK
      for (int i = tid; i < K[l2]; i += 1024)
        dst[i] = ksc_g[(size_t)bl * 1024 + i];
    } else {        // cross-block within kernel: RMW read (XCD-safe)
      float* srcp = ksc_g + (size_t)(b * NLEV + l2) * 1024;
      for (int i = tid; i < K[l2]; i += 1024)
        dst[i] = atomicAdd(&srcp[i], 0.0f);   // scores > 0, +0.0 exact
    }
  }
  __syncthreads();
  if (tid < K[l]) {
    float s = ksc[l * 1024 + tid];
    int rank = tid;  // within-level kept ties: earlier topk rank first
    for (int l2 = 0; l2 < NLEV; ++l2) {
      if (l2 == l) continue;
      const float* A = ksc + l2 * 1024;
      rank += (l2 < l) ? cnt_ge(A, K[l2], s) : cnt_gt(A, K[l2], s);
    }
    if (rank < 1000) {
      int j = kj_g[(size_t)bl * 1024 + tid];
      float4 bx = lvlraw[(size_t)bl * 1024 + j];
      float* op = out + (size_t)b * 5000 + (size_t)rank * 5;
      op[0] = bx.x; op[1] = bx.y; op[2] = bx.z; op[3] = bx.w; op[4] = s;
    }
  }
}

extern "C" void kernel_launch(void* const* d_in, const int* in_sizes, int n_in,
                              void* d_out, int out_size, void* d_ws, size_t ws_size,
                              hipStream_t stream) {
  const float* obj     = (const float*)d_in[0];
  const float* deltas  = (const float*)d_in[1];
  const float* anchors = (const float*)d_in[2];
  float* out = (float*)d_out;

  // workspace layout (~11 MB; descending alignment order)
  char* p = (char*)d_ws;
  float4* box0   = (float4*)p; p += (size_t)40 * 1024 * sizeof(float4);
  float4* lvlraw = (float4*)p; p += (size_t)40 * 1024 * sizeof(float4);
  unsigned long long* cand_g = (unsigned long long*)p; p += (size_t)40 * RCAP * 8;
  unsigned long long* masks  = (unsigned long long*)p; p += (size_t)40 * 16 * 1024 * 8;
  int*   hist_g = (int*)p;   p += (size_t)104 * 4096 * 4;
  int*   cnt_g  = (int*)p;   p += 40 * 4;
  float* maxblk = (float*)p; p += (size_t)40 * NPARTS * 4;
  float* sc0    = (float*)p; p += (size_t)40 * 1024 * 4;
  float* lvlsc  = (float*)p; p += (size_t)40 * 1024 * 4;
  int*   g_V    = (int*)p;   p += 40 * 4;
  float* ksc_g  = (float*)p; p += (size_t)40 * 1024 * 4;
  int*   kj_g   = (int*)p;   p += (size_t)40 * 1024 * 4;
  int*   K_g    = (int*)p;   p += 40 * 4;
  int*   done   = (int*)p;   p += BATCH * 4;

  hipLaunchKernelGGL(k_hist, dim3(BATCH * 13), dim3(1024), 0, stream,
                     obj, hist_g, cnt_g, maxblk, done, out);
  hipLaunchKernelGGL(k_collect, dim3(BATCH * 13), dim3(1024), 0, stream,
                     obj, hist_g, cnt_g, cand_g);
  hipLaunchKernelGGL(k_rankdec, dim3(BATCH * NLEV * NPARTS), dim3(256), 0, stream,
                     cand_g, cnt_g, deltas, anchors, sc0, box0, maxblk);
  hipLaunchKernelGGL(k_mask, dim3(BATCH * NLEV * MSPLIT), dim3(1024), 0, stream,
                     sc0, box0, maxblk, lvlsc, lvlraw, g_V, masks);
  hipLaunchKernelGGL(k_tail, dim3(BATCH * NLEV), dim3(1024), 0, stream,
                     masks, g_V, lvlsc, ksc_g, kj_g, K_g, done, lvlraw, out);
}

// Round 9
// 193.469 us; speedup vs baseline: 1.3015x; 1.0404x over previous
//
#include <hip/hip_runtime.h>
#include <math.h>

#pragma clang fp contract(off)

#define A_TOTAL 196416
#define BATCH 8
#define KTOT 4576
#define NLEV 5
#define MSPLIT 16
#define RCAP 6144        // per-(b,l) candidate cap (typical cnt ~1.2k)
#define NPARTS 12        // rank parts: 12*512 == RCAP (256-thr blocks, 2 elems/thr)

static __device__ const int d_aoff[NLEV] = {0, 147456, 184320, 193536, 195840};
static __device__ const int d_n[NLEV]    = {147456, 36864, 9216, 2304, 576};
static __device__ const int d_k[NLEV]    = {1000, 1000, 1000, 1000, 576};
// histogram slice-splits per level (13 parts per batch)
static __device__ const int d_spl[NLEV]  = {8, 2, 1, 1, 1};
static __device__ const int d_bp[NLEV]   = {0, 8, 10, 11, 12};
static __device__ const int d_pb_l[13]    = {0,0,0,0,0,0,0,0,1,1,2,3,4};
static __device__ const int d_pb_part[13] = {0,1,2,3,4,5,6,7,0,1,0,0,0};

// Exact-equivalence constant for "RN(inter/denom) > 0.7f":
//   RN(q) > 0.7f  <=>  q >= midpoint(0.7f, nextafter(0.7f))  <=>
//   (double)inter >= TM_IOU * (double)denom  exactly (<=49 sig bits).
#define TM_IOU (0.699999988079071044921875 + 0x1p-25)

// monotone map: f32 -> u32 preserving order (no NaNs in this data); invertible
__device__ inline unsigned int mono(float f) {
  unsigned int u = __float_as_uint(f);
  return (u & 0x80000000u) ? ~u : (u | 0x80000000u);
}
__device__ inline float imono(unsigned int m) {
  return __uint_as_float((m & 0x80000000u) ? (m & 0x7FFFFFFFu) : ~m);
}

// binary searches on a descending-sorted array
__device__ inline int cnt_gt(const float* A, int n, float s) {  // #{A[i] > s}
  int lo = 0, hi = n;
  while (lo < hi) { int mid = (lo + hi) >> 1; if (A[mid] > s) lo = mid + 1; else hi = mid; }
  return lo;
}
__device__ inline int cnt_ge(const float* A, int n, float s) {  // #{A[i] >= s}
  int lo = 0, hi = n;
  while (lo < hi) { int mid = (lo + hi) >> 1; if (A[mid] >= s) lo = mid + 1; else hi = mid; }
  return lo;
}

// ---------------------------------------------------------------------------
// K1: per-(b,l,part) private 4096-bin histogram of mono(obj) top-12 bits.
// Block 0 zero-inits cnt_g and maxblk; the pb==0 block of each batch also
// zero-fills that batch's output slice (removes the zero-fill from the tail).
// ---------------------------------------------------------------------------
__global__ __launch_bounds__(1024) void k_hist(const float* __restrict__ obj,
                                               int* __restrict__ hist_g,
                                               int* __restrict__ cnt_g,
                                               float* __restrict__ maxblk,
                                               float* __restrict__ out) {
  int blk = blockIdx.x;
  int tid = threadIdx.x;
  if (blk == 0) {
    for (int i = tid; i < 40 * NPARTS; i += 1024) maxblk[i] = 0.0f;
    for (int i = tid; i < 40; i += 1024) cnt_g[i] = 0;
  }
  int b = blk / 13, pb = blk % 13;
  if (pb == 0) {
    float* ob = out + (size_t)b * 5000;
    for (int i = tid; i < 5000; i += 1024) ob[i] = 0.0f;
  }
  int l = d_pb_l[pb], part = d_pb_part[pb];
  int slice = d_n[l] / d_spl[l];
  int start = d_aoff[l] + part * slice;
  const float4* p4 = (const float4*)(obj + (size_t)b * A_TOTAL + start);
  int s4 = slice >> 2;
  __shared__ int h[4096];
  for (int i = tid; i < 4096; i += 1024) h[i] = 0;
  __syncthreads();
  for (int i = tid; i < s4; i += 1024) {
    float4 v = p4[i];
    atomicAdd(&h[mono(v.x) >> 20], 1);
    atomicAdd(&h[mono(v.y) >> 20], 1);
    atomicAdd(&h[mono(v.z) >> 20], 1);
    atomicAdd(&h[mono(v.w) >> 20], 1);
  }
  __syncthreads();
  int* outp = hist_g + (size_t)blk * 4096;
  for (int i = tid; i < 4096; i += 1024) outp[i] = h[i];
}

// ---------------------------------------------------------------------------
// K2: collect candidates (single cand_g + cnt_g). Threshold derivation is
// WAVE-PARALLEL (R5, verified). Wave-aggregated slot allocation; fast path:
// one combined ballot per float4 group.
// ---------------------------------------------------------------------------
__global__ __launch_bounds__(1024) void k_collect(const float* __restrict__ obj,
                                                  const int* __restrict__ hist_g,
                                                  int* __restrict__ cnt_g,
                                                  unsigned long long* __restrict__ cand_g) {
  int blk = blockIdx.x;
  int b = blk / 13, pb = blk % 13;
  int l = d_pb_l[pb], part = d_pb_part[pb];
  int bl = b * NLEV + l;
  const int k = d_k[l];
  int tid = threadIdx.x, lane = tid & 63;
  __shared__ int t[4096];
  __shared__ int grp[256];
  __shared__ unsigned int sP;
  __shared__ __align__(16) unsigned long long lbuf[RCAP];  // 48 KB
  __shared__ int s_cnt, s_base;
  int parts = d_spl[l];
  const int* hb = hist_g + (size_t)(b * 13 + d_bp[l]) * 4096;
  for (int bin = tid; bin < 4096; bin += 1024) {
    int s = 0;
    for (int p = 0; p < parts; ++p) s += hb[p * 4096 + bin];
    t[bin] = s;
  }
  if (tid == 0) s_cnt = 0;
  __syncthreads();
  if (tid < 256) {
    int s = 0;
    for (int j = 0; j < 16; ++j) s += t[tid * 16 + j];
    grp[tid] = s;
  }
  __syncthreads();
  if (tid < 64) {  // wave 0: parallel threshold find
    int g0 = grp[4 * tid], g1 = grp[4 * tid + 1];
    int g2 = grp[4 * tid + 2], g3 = grp[4 * tid + 3];
    int q = g0 + g1 + g2 + g3;
    int x = q;  // inclusive suffix-sum over lanes
#pragma unroll
    for (int off = 1; off < 64; off <<= 1) {
      int y = __shfl_down(x, off);
      if (tid + off < 64) x += y;
    }
    int Qn = x - q;
    int best = -1;
    if (x >= k) best = 4 * tid;
    if (g1 + g2 + g3 + Qn >= k) best = 4 * tid + 1;
    if (g2 + g3 + Qn >= k) best = 4 * tid + 2;
    if (g3 + Qn >= k) best = 4 * tid + 3;
#pragma unroll
    for (int off = 1; off < 64; off <<= 1) best = max(best, __shfl_xor(best, off));
    int gstar = best;  // >= 0 (total >= k guaranteed)
    int partl = 0;
    if (4 * tid > gstar) partl += g0;
    if (4 * tid + 1 > gstar) partl += g1;
    if (4 * tid + 2 > gstar) partl += g2;
    if (4 * tid + 3 > gstar) partl += g3;
#pragma unroll
    for (int off = 1; off < 64; off <<= 1) partl += __shfl_xor(partl, off);
    int cum = partl;
    int tb = (tid < 16) ? t[gstar * 16 + tid] : 0;
    int Tx = tb;
#pragma unroll
    for (int off = 1; off < 16; off <<= 1) {
      int y = __shfl_down(Tx, off);
      if (tid + off < 16) Tx += y;
    }
    int bestd = -1;
    if (tid < 16 && cum + Tx >= k) bestd = tid;
#pragma unroll
    for (int off = 1; off < 64; off <<= 1) bestd = max(bestd, __shfl_xor(bestd, off));
    if (tid == 0) sP = (unsigned int)(gstar * 16 + bestd);
  }
  __syncthreads();
  unsigned int P = sP;  // take keys with (key>>20) >= P; count >= k guaranteed
  int slice = d_n[l] / parts;
  int start = d_aoff[l] + part * slice;
  const float4* p4 = (const float4*)(obj + (size_t)b * A_TOTAL + start);
  int s4 = slice >> 2;
  int lbase = part * slice;  // level-local base index
  for (int i = tid; i < s4; i += 1024) {
    float4 v = p4[i];
    unsigned int a[4] = {mono(v.x), mono(v.y), mono(v.z), mono(v.w)};
    bool q0 = (a[0] >> 20) >= P, q1 = (a[1] >> 20) >= P;
    bool q2 = (a[2] >> 20) >= P, q3 = (a[3] >> 20) >= P;
    if (__ballot(q0 | q1 | q2 | q3)) {  // wave-uniform; rare
      bool qs[4] = {q0, q1, q2, q3};
#pragma unroll
      for (int c = 0; c < 4; ++c) {
        unsigned long long mb = __ballot(qs[c]);
        if (mb) {
          int base;
          if (lane == 0) base = atomicAdd(&s_cnt, __popcll(mb));
          base = __shfl(base, 0);
          if (qs[c]) {
            int slot = base + __popcll(mb & ((1ull << lane) - 1ull));
            if (slot < RCAP) {
              int idx = lbase + 4 * i + c;
              lbuf[slot] = ((unsigned long long)a[c] << 32) |
                           (unsigned int)(~(unsigned int)idx);
            }
          }
        }
      }
    }
  }
  __syncthreads();
  int cnt = min(s_cnt, RCAP);
  if (tid == 0) s_base = atomicAdd(&cnt_g[bl], cnt);  // one global atomic/block
  __syncthreads();
  int base = s_base;
  for (int i = tid; i < cnt; i += 1024) {
    int slot = base + i;
    if (slot < RCAP) cand_g[(size_t)bl * RCAP + slot] = lbuf[i];
  }
}

// ---------------------------------------------------------------------------
// K3 helper: rank<k -> decode+clip+sigmoid inline; returns max coord (or 0).
// ---------------------------------------------------------------------------
__device__ inline float decode_emit(unsigned long long e, int rank, int b,
                                    int k, int aoff, int bl,
                                    const float* __restrict__ deltas,
                                    const float* __restrict__ anchors,
                                    float* __restrict__ sc0,
                                    float4* __restrict__ box0) {
  if (rank >= k) return 0.0f;
  unsigned int k32 = (unsigned int)(e >> 32);
  unsigned int idx = ~(unsigned int)(e & 0xFFFFFFFFull);
  float o = imono(k32);                       // exact objectness value
  int gidx = aoff + (int)idx;
  const float* dl = deltas + ((size_t)b * A_TOTAL + gidx) * 4;
  const float* an = anchors + (size_t)gidx * 4;
  float a0 = an[0], a1 = an[1], a2 = an[2], a3 = an[3];
  float wa = a2 - a0, ha = a3 - a1;
  float cxa = a0 + 0.5f * wa, cya = a1 + 0.5f * ha;
  float dx = dl[0], dy = dl[1];
  const float CLIPV = 4.135166556742356f;  // log(1000/16)
  float dw = fminf(dl[2], CLIPV), dh = fminf(dl[3], CLIPV);
  float pcx = dx * wa + cxa;               // contract(off): mul+add like numpy
  float pcy = dy * ha + cya;
  float pw = (float)exp((double)dw) * wa;  // correctly-rounded f32 exp
  float ph = (float)exp((double)dh) * ha;
  float x1 = pcx - 0.5f * pw, y1 = pcy - 0.5f * ph;
  float x2 = pcx + 0.5f * pw, y2 = pcy + 0.5f * ph;
  x1 = fminf(fmaxf(x1, 0.0f), 1024.0f);
  x2 = fminf(fmaxf(x2, 0.0f), 1024.0f);
  y1 = fminf(fmaxf(y1, 0.0f), 768.0f);
  y2 = fminf(fmaxf(y2, 0.0f), 768.0f);
  float s = (float)(1.0 / (1.0 + exp(-(double)o)));  // correctly-rounded sigmoid
  bool valid = ((x2 - x1) >= 1.0f) && ((y2 - y1) >= 1.0f) && (s >= 0.0f);
  sc0[bl * 1024 + rank] = valid ? s : -1.0f;
  box0[bl * 1024 + rank] = make_float4(x1, y1, x2, y2);
  return fmaxf(fmaxf(x1, y1), fmaxf(x2, y2));
}

// ---------------------------------------------------------------------------
// K3: rank candidates + inline decode — u64 all-pairs on LDS-staged keys,
// EXACT R4 form (empirically fastest across R2/R5/R6/R7 alternatives: the
// uniform-trip-count loop + LDS broadcast stream is what the compiler
// pipelines best). 256 thr x 2 elems, NPARTS=12.
// ---------------------------------------------------------------------------
__global__ __launch_bounds__(256) void k_rankdec(const unsigned long long* __restrict__ cand_g,
                                                 const int* __restrict__ cnt_g,
                                                 const float* __restrict__ deltas,
                                                 const float* __restrict__ anchors,
                                                 float* __restrict__ sc0,
                                                 float4* __restrict__ box0,
                                                 float* __restrict__ maxblk) {
  int bl = blockIdx.x / NPARTS, part = blockIdx.x % NPARTS;
  int b = bl / NLEV, l = bl % NLEV;
  const int k = d_k[l], aoff = d_aoff[l];
  int cnt = min(cnt_g[bl], RCAP);
  if (part * 512 >= cnt) return;  // uniform; maxblk[blk] stays 0 (pre-zeroed)
  __shared__ __align__(16) unsigned long long cb[RCAP];  // 48 KB
  __shared__ unsigned int s_max;
  int tid = threadIdx.x;
  if (tid == 0) s_max = 0u;
  const unsigned long long* src = cand_g + (size_t)bl * RCAP;
  {  // vectorized staging (16B): src is 16B-aligned (bl*RCAP*8, RCAP even)
    const ulonglong2* s2 = (const ulonglong2*)src;
    ulonglong2* d2 = (ulonglong2*)cb;
    int n2 = cnt >> 1;
    for (int i = tid; i < n2; i += 256) d2[i] = s2[i];
    if ((cnt & 1) && tid == 0) cb[cnt - 1] = src[cnt - 1];
  }
  __syncthreads();
  int i0 = part * 512 + tid, i1 = i0 + 256;
  unsigned long long e0 = ~0ull, e1 = ~0ull;  // sentinels; emission gated below
  if (i0 < cnt) e0 = cb[i0];
  if (i1 < cnt) e1 = cb[i1];
  int r0 = 0, r1 = 0;
  int nc2 = cnt >> 1;
  const ulonglong2* c2 = (const ulonglong2*)cb;
  for (int j = 0; j < nc2; ++j) {
    ulonglong2 v = c2[j];
    r0 += (v.x > e0) + (v.y > e0);
    r1 += (v.x > e1) + (v.y > e1);
  }
  if (cnt & 1) {
    unsigned long long v = cb[cnt - 1];
    r0 += (v > e0);
    r1 += (v > e1);
  }
  float mx = 0.0f;
  if (i0 < cnt) mx = fmaxf(mx, decode_emit(e0, r0, b, k, aoff, bl, deltas, anchors, sc0, box0));
  if (i1 < cnt) mx = fmaxf(mx, decode_emit(e1, r1, b, k, aoff, bl, deltas, anchors, sc0, box0));
#pragma unroll
  for (int s = 1; s < 64; s <<= 1) mx = fmaxf(mx, __shfl_xor(mx, s));
  if ((tid & 63) == 0) atomicMax(&s_max, __float_as_uint(mx));  // 4 atomics/block
  __syncthreads();
  if (tid == 0) maxblk[blockIdx.x] = __uint_as_float(s_max);
}

// ---------------------------------------------------------------------------
// K4: fused compact + mask. Each of the 16 part-blocks per (b,l) redoes the
// one-ballot valid-compaction into LDS (offset-added boxes, topk order);
// part 0 also emits lvlsc/lvlraw/g_V. Then wave w computes suppression word w
// for its 64 rows (word-major masks[bl][word][row]). NMS over valids only is
// exact: invalids start suppressed and are inert.
// ---------------------------------------------------------------------------
__global__ __launch_bounds__(1024) void k_mask(const float* __restrict__ sc0,
                                               const float4* __restrict__ box0,
                                               const float* __restrict__ maxblk,
                                               float* __restrict__ lvlsc,
                                               float4* __restrict__ lvlraw,
                                               int* __restrict__ g_V,
                                               unsigned long long* __restrict__ masks) {
  int blk = blockIdx.x;
  int bl = blk / MSPLIT, part = blk % MSPLIT;
  int b = bl / NLEV, l = bl % NLEV;
  const int k = d_k[l];
  int tid = threadIdx.x, lane = tid & 63, w = tid >> 6;
  __shared__ float4 lbox[1024];
  __shared__ float s_mv;
  __shared__ int s_wcnt[16];
  if (w == 0) {  // reduce maxblk[b*60 .. b*60+60)
    float v = 0.0f;
    for (int i = lane; i < NLEV * NPARTS; i += 64)
      v = fmaxf(v, maxblk[b * (NLEV * NPARTS) + i]);
#pragma unroll
    for (int s = 1; s < 64; s <<= 1) v = fmaxf(v, __shfl_xor(v, s));
    if (lane == 0) s_mv = v;
  }
  bool in = tid < k;
  float s = in ? sc0[bl * 1024 + tid] : -1.0f;
  bool valid = in && (s >= 0.0f);
  unsigned long long mb = __ballot(valid);
  if (lane == 0) s_wcnt[w] = __popcll(mb);
  __syncthreads();
  int pre = 0;
  for (int ww = 0; ww < w; ++ww) pre += s_wcnt[ww];
  int j = pre + __popcll(mb & ((1ull << lane) - 1ull));
  int V = 0;
  for (int ww = 0; ww < 16; ++ww) V += s_wcnt[ww];
  float off = (float)l * (s_mv + 1.0f);
  if (valid) {
    float4 bx = box0[bl * 1024 + tid];
    lbox[j] = make_float4(bx.x + off, bx.y + off, bx.z + off, bx.w + off);
    if (part == 0) {
      lvlsc[bl * 1024 + j] = s;
      lvlraw[bl * 1024 + j] = bx;
    }
  }
  if (part == 0 && tid == 0) g_V[bl] = V;
  __syncthreads();
  int row0 = part * 64;
  if (row0 >= V) return;                      // block-uniform; barriers done
  int i = row0 + lane;                        // my row
  if (i >= V) return;                         // per-lane exit after last barrier
  float4 bb = lbox[i];
  float ba = (bb.z - bb.x) * (bb.w - bb.y);
  unsigned long long bits = 0ull;
  int jbase = w * 64;
  if (jbase + 63 > i && jbase < V) {
    int jhi = min(64, V - jbase);
    for (int jo = 0; jo < jhi; ++jo) {        // jj uniform across the wave
      int jj = jbase + jo;
      float4 cb = lbox[jj];
      float ca = (cb.z - cb.x) * (cb.w - cb.y);
      float xx1 = fmaxf(bb.x, cb.x), yy1 = fmaxf(bb.y, cb.y);
      float xx2 = fminf(bb.z, cb.z), yy2 = fminf(bb.w, cb.w);
      float wd = fmaxf(xx2 - xx1, 0.0f), ht = fmaxf(yy2 - yy1, 0.0f);
      float inter = wd * ht;
      float denom = fmaxf(ba + ca - inter, 1e-9f);
      if ((jj > i) && ((double)inter >= TM_IOU * (double)denom)) bits |= (1ull << jo);
    }
  }
  masks[((size_t)bl * 16 + w) * 1024 + i] = bits;  // coalesced across lanes
}

// ---------------------------------------------------------------------------
// K5: serial bitmask scan over V valids, one 16-wave block per (b,l) (R4
// version). val loads software-pipelined one chunk ahead. Ends with
// ballot-compaction of kept entries to ksc_g/kj_g/K_g via PLAIN stores —
// visibility to k_merge comes from the kernel boundary (R8's atomic publish
// measured +16 µs; reverted).
// ---------------------------------------------------------------------------
__global__ __launch_bounds__(1024) void k_scan(const unsigned long long* __restrict__ masks,
                                               const int* __restrict__ g_V,
                                               const float* __restrict__ lvlsc,
                                               float* __restrict__ ksc_g,
                                               int* __restrict__ kj_g,
                                               int* __restrict__ K_g) {
  int bl = blockIdx.x;
  int tid = threadIdx.x, lane = tid & 63, w = tid >> 6;
  int V = g_V[bl];
  const int nch = (V + 63) / 64;
  const unsigned long long* M = masks + (size_t)bl * 16 * 1024;
  __shared__ unsigned long long s_remv[16];
  __shared__ unsigned long long s_D[2][72];   // 64 + 8 pad (scan prefetch)
  __shared__ unsigned long long s_dw;
  __shared__ int s_wcnt[16];
  if (tid < 16) s_remv[tid] = ~0ull;          // words beyond nch: nothing kept
  int base_w = w * 64;
  unsigned long long init_w;
  if (V <= base_w) init_w = ~0ull;
  else if (V >= base_w + 64) init_w = 0ull;
  else init_w = (~0ull) << (V - base_w);
  if (w == 0 && nch > 0) s_D[0][lane] = (lane < V) ? M[lane] : 0ull;
  if (tid < 8) { s_D[0][64 + tid] = 0ull; s_D[1][64 + tid] = 0ull; }
  unsigned long long acc = 0ull;
  unsigned long long val_next = 0ull;
  if (w > 0 && w < nch && lane < V) val_next = M[(size_t)w * 1024 + lane];
  __syncthreads();

  for (int c = 0; c < nch; ++c) {
    unsigned long long val = val_next;
    val_next = 0ull;                          // prefetch val for chunk c+1
    int rn = 64 * (c + 1) + lane;
    if (w > c + 1 && w < nch && rn < V) val_next = M[(size_t)w * 1024 + rn];
    if (w == c) {
      unsigned long long red = acc;
#pragma unroll
      for (int s = 1; s < 64; s <<= 1) red |= __shfl_xor(red, s);
      unsigned long long dw = init_w | red;
      const unsigned long long* D = s_D[c & 1];
      unsigned long long pb[8];
#pragma unroll
      for (int u = 0; u < 8; ++u) pb[u] = D[u];
#pragma unroll
      for (int g = 0; g < 8; ++g) {
#pragma unroll
        for (int u = 0; u < 8; ++u) {
          int jj = g * 8 + u;
          if (!((dw >> jj) & 1ull)) dw |= pb[u];
          pb[u] = D[jj + 8];  // decision-independent prefetch (padded)
        }
      }
      if (lane == 0) { s_dw = dw; s_remv[c] = dw; }
    }
    if (w == c + 1 && w < nch) {
      int rr = 64 * (c + 1) + lane;
      s_D[(c + 1) & 1][lane] = (rr < V) ? M[(size_t)(c + 1) * 1024 + rr] : 0ull;
    }
    __syncthreads();
    if (w > c && w < nch) {
      unsigned long long kept = ~s_dw;
      if ((kept >> lane) & 1ull) acc |= val;
    }
    __syncthreads();  // protect s_dw before next chunk overwrites it
  }

  // ---- fused compaction of kept entries (topk order preserved) ----
  unsigned long long kb = ~s_remv[w];         // rows >= V stay suppressed
  bool kept = ((kb >> lane) & 1ull) != 0ull;
  unsigned long long mb = __ballot(kept);
  if (lane == 0) s_wcnt[w] = __popcll(mb);
  __syncthreads();
  int pre = 0;
  for (int ww = 0; ww < w; ++ww) pre += s_wcnt[ww];
  int r = pre + __popcll(mb & ((1ull << lane) - 1ull));
  if (kept) {
    ksc_g[bl * 1024 + r] = lvlsc[bl * 1024 + tid];
    kj_g[bl * 1024 + r] = tid;
  }
  if (tid == 0) {
    int t = 0;
    for (int ww = 0; ww < 16; ++ww) t += s_wcnt[ww];
    K_g[bl] = t;
  }
}

// ---------------------------------------------------------------------------
// K6: merge. One block per (b,l) — 40-way parallel. Loads the batch's 5
// compacted score lists into LDS, computes global output rank only for its
// own level's kept entries (5-way stable merge: cnt_ge for earlier levels /
// cnt_gt for later), scatters rows with rank<1000. Zeros pre-written by
// k_hist; each rank<1000 cell written by exactly one (level, i).
// ---------------------------------------------------------------------------
__global__ __launch_bounds__(1024) void k_merge(const float* __restrict__ ksc_g,
                                                const int* __restrict__ kj_g,
                                                const int* __restrict__ K_g,
                                                const float4* __restrict__ lvlraw,
                                                float* __restrict__ out) {
  int blk = blockIdx.x;
  int b = blk / NLEV, l = blk % NLEV;
  int tid = threadIdx.x;
  __shared__ float ksc[NLEV * 1024];  // 20 KB
  __shared__ int sK[NLEV];
  if (tid < NLEV) sK[tid] = K_g[b * NLEV + tid];
  __syncthreads();
  int K[NLEV];
  for (int l2 = 0; l2 < NLEV; ++l2) K[l2] = sK[l2];
  for (int l2 = 0; l2 < NLEV; ++l2) {
    for (int i = tid; i < K[l2]; i += 1024)
      ksc[l2 * 1024 + i] = ksc_g[(size_t)(b * NLEV + l2) * 1024 + i];
  }
  __syncthreads();
  if (tid < K[l]) {
    float s = ksc[l * 1024 + tid];
    int rank = tid;  // within-level kept ties: earlier topk rank first
    for (int l2 = 0; l2 < NLEV; ++l2) {
      if (l2 == l) continue;
      const float* A = ksc + l2 * 1024;
      rank += (l2 < l) ? cnt_ge(A, K[l2], s) : cnt_gt(A, K[l2], s);
    }
    if (rank < 1000) {
      int j = kj_g[(size_t)(b * NLEV + l) * 1024 + tid];
      float4 bx = lvlraw[(size_t)(b * NLEV + l) * 1024 + j];
      float* op = out + (size_t)b * 5000 + (size_t)rank * 5;
      op[0] = bx.x; op[1] = bx.y; op[2] = bx.z; op[3] = bx.w; op[4] = s;
    }
  }
}

extern "C" void kernel_launch(void* const* d_in, const int* in_sizes, int n_in,
                              void* d_out, int out_size, void* d_ws, size_t ws_size,
                              hipStream_t stream) {
  const float* obj     = (const float*)d_in[0];
  const float* deltas  = (const float*)d_in[1];
  const float* anchors = (const float*)d_in[2];
  float* out = (float*)d_out;

  // workspace layout (~11 MB; descending alignment order)
  char* p = (char*)d_ws;
  float4* box0   = (float4*)p; p += (size_t)40 * 1024 * sizeof(float4);
  float4* lvlraw = (float4*)p; p += (size_t)40 * 1024 * sizeof(float4);
  unsigned long long* cand_g = (unsigned long long*)p; p += (size_t)40 * RCAP * 8;
  unsigned long long* masks  = (unsigned long long*)p; p += (size_t)40 * 16 * 1024 * 8;
  int*   hist_g = (int*)p;   p += (size_t)104 * 4096 * 4;
  int*   cnt_g  = (int*)p;   p += 40 * 4;
  float* maxblk = (float*)p; p += (size_t)40 * NPARTS * 4;
  float* sc0    = (float*)p; p += (size_t)40 * 1024 * 4;
  float* lvlsc  = (float*)p; p += (size_t)40 * 1024 * 4;
  int*   g_V    = (int*)p;   p += 40 * 4;
  float* ksc_g  = (float*)p; p += (size_t)40 * 1024 * 4;
  int*   kj_g   = (int*)p;   p += (size_t)40 * 1024 * 4;
  int*   K_g    = (int*)p;   p += 40 * 4;

  hipLaunchKernelGGL(k_hist, dim3(BATCH * 13), dim3(1024), 0, stream,
                     obj, hist_g, cnt_g, maxblk, out);
  hipLaunchKernelGGL(k_collect, dim3(BATCH * 13), dim3(1024), 0, stream,
                     obj, hist_g, cnt_g, cand_g);
  hipLaunchKernelGGL(k_rankdec, dim3(BATCH * NLEV * NPARTS), dim3(256), 0, stream,
                     cand_g, cnt_g, deltas, anchors, sc0, box0, maxblk);
  hipLaunchKernelGGL(k_mask, dim3(BATCH * NLEV * MSPLIT), dim3(1024), 0, stream,
                     sc0, box0, maxblk, lvlsc, lvlraw, g_V, masks);
  hipLaunchKernelGGL(k_scan, dim3(BATCH * NLEV), dim3(1024), 0, stream,
                     masks, g_V, lvlsc, ksc_g, kj_g, K_g);
  hipLaunchKernelGGL(k_merge, dim3(BATCH * NLEV), dim3(1024), 0, stream,
                     ksc_g, kj_g, K_g, lvlraw, out);
}